// Round 1
// baseline (53.147 us; speedup 1.0000x reference)
//
#include <hip/hip_runtime.h>
#include <hip/hip_bf16.h>
#include <math.h>

// SOAP descriptor (radial GTO part) for N=3072 atoms, diagonal periodic box.
// out[i, n*N + j] = mask(d_ij) ? (d_ij/RCUT)^n * exp(-alpha*d_ij^2) : 0
// out[i, 8*N + l] = 0  (l = 0..6, "angular" zeros)
// Row length M = 8*N + 7 = 24583; out is float32, 302 MB -> store-BW bound.

#define N_ATOMS 3072
#define NMAX    8
#define LP1     7              // LMAX+1
#define ROWLEN  (NMAX * N_ATOMS + LP1)   // 24583
#define RCUT_F  6.0f
#define ALPHA_F 2.0f           // 0.5 / sigma^2, sigma=0.5

__global__ __launch_bounds__(256)
void soap_kernel(const float* __restrict__ pos,
                 const float* __restrict__ cell,
                 float* __restrict__ out) {
    const int i = blockIdx.x;
    const int j = blockIdx.y * blockDim.x + threadIdx.x;

    // diagonal cell (input is BOX * eye(3))
    const float c0 = cell[0], c1 = cell[4], c2 = cell[8];

    const float pix = pos[3 * i + 0];
    const float piy = pos[3 * i + 1];
    const float piz = pos[3 * i + 2];
    const float pjx = pos[3 * j + 0];
    const float pjy = pos[3 * j + 1];
    const float pjz = pos[3 * j + 2];

    float dx = pix - pjx;
    float dy = piy - pjy;
    float dz = piz - pjz;
    // minimum image (round-to-nearest-even matches jnp.round; ties can't
    // matter: a tie means wrapped |comp| = box/2 = 15 > rcut -> masked)
    dx -= c0 * rintf(dx / c0);
    dy -= c1 * rintf(dy / c1);
    dz -= c2 * rintf(dz / c2);

    const float d2 = dx * dx + dy * dy + dz * dz + 1e-10f;
    const float d  = sqrtf(d2);
    const bool  m  = (d < RCUT_F) && (d > 0.1f);

    const float base = m ? expf(-ALPHA_F * d2) : 0.0f;
    const float r    = d * (1.0f / RCUT_F);

    size_t off = (size_t)i * ROWLEN + (size_t)j;
    float v = base;              // n = 0 term: (d/rcut)^0 * exp(...)
#pragma unroll
    for (int n = 0; n < NMAX; ++n) {
        out[off] = v;
        v *= r;
        off += N_ATOMS;
    }

    // angular zeros (7 per row), written once per row by block y==0
    if (blockIdx.y == 0 && threadIdx.x < LP1) {
        out[(size_t)i * ROWLEN + (size_t)(NMAX * N_ATOMS) + threadIdx.x] = 0.0f;
    }
}

extern "C" void kernel_launch(void* const* d_in, const int* in_sizes, int n_in,
                              void* d_out, int out_size, void* d_ws, size_t ws_size,
                              hipStream_t stream) {
    const float* pos  = (const float*)d_in[0];
    // d_in[1] = atom_types (unused by the math)
    const float* cell = (const float*)d_in[2];
    float* out = (float*)d_out;

    dim3 block(256);
    dim3 grid(N_ATOMS, N_ATOMS / 256);   // 3072 x 12 blocks
    soap_kernel<<<grid, block, 0, stream>>>(pos, cell, out);
}